// Round 9
// baseline (503.974 us; speedup 1.0000x reference)
//
#include <hip/hip_runtime.h>

// Centroids: argmin_c ||latent[r] - coords[c]||^2, 131072 rows x 2048 coords, D=128.
//
// prep_coords: coords -> bf16 hi/lo "B images" (XOR-swizzled granules: contiguous
//   staging AND conflict-free frag ds_read_b128), + biased c2 (+320), counter=0.
// centroid_fast (R6 structure: single buffer, 2 barriers/chunk — R8 lesson:
//   source-level double-buffering was neutral-to-negative, m97 plateau):
//   - wave owns 32 rows x all 64 chunk-cols; A frags bf16x2 in VGPRs (64).
//   - B staged via __builtin_amdgcn_global_load_lds width=16 (8 DMA/wave/chunk,
//     kills the staging VALU that made R8 VALU-co-bound at 46%).
//   - bf16x2 3-pass MFMA (Ahh+Ahl+Alh), rigorous err <= ~0.006.
//   - PACKED epilogue: score = c2b[col] - 2*cross (c2b biased +320 => positive),
//     low 11 mantissa bits replaced by col index -> b1/b2 are pure v_min_f32
//     chains, first-index tie-break for free. Pack err <= 0.125.
//   - flag rows with packed gap < 0.30 (covers 2*0.125 + algo err).
// refine_fp64: batched 4 rows/block exact fp64 argmin for flagged rows (~3%).
//
// ws layout (bytes): 0 c2 | 8192 counter | 16384 worklist(128KB) |
//                    262144 Bh (512KB) | 786432 Bl (512KB) | end 1310720

constexpr int D = 128;
constexpr int C = 2048;
constexpr int NCH = 64;            // coords per chunk
constexpr int NCHUNKS = C / NCH;   // 32
constexpr float BIAS   = 320.0f;   // keeps all scores positive (min score ~ +90)
constexpr float MARGIN = 0.30f;    // >= 2*pack_err(0.125) + algo_err(0.006)
constexpr int WL_CAP = 32768;

constexpr size_t WS_CNT = 8192;
constexpr size_t WS_WL  = 16384;
constexpr size_t WS_BH  = 262144;
constexpr size_t WS_BL  = 786432;

typedef __attribute__((ext_vector_type(8))) short short8;
typedef __attribute__((ext_vector_type(4))) float f32x4;

__device__ inline unsigned short bf16_rne(float x) {
    unsigned u = __float_as_uint(x);
    u += 0x7FFFu + ((u >> 16) & 1u);
    return (unsigned short)(u >> 16);
}
__device__ inline float bf16_to_f(unsigned short h) {
    return __uint_as_float(((unsigned)h) << 16);
}
__device__ inline void split8(const float* v, short8* hi, short8* lo) {
#pragma unroll
    for (int j = 0; j < 8; ++j) {
        unsigned short h = bf16_rne(v[j]);
        (*hi)[j] = (short)h;
        (*lo)[j] = (short)bf16_rne(v[j] - bf16_to_f(h));
    }
}

// async 16B/lane global->LDS DMA; LDS dst = wave-uniform base + lane*16
__device__ inline void async_copy16(const void* g, void* l) {
    __builtin_amdgcn_global_load_lds(
        (const __attribute__((address_space(1))) void*)g,
        (__attribute__((address_space(3))) void*)l, 16, 0, 0);
}

// ---------------- prep: B images + biased c2 ----------------
// 32768 threads: thread t -> coord c = t>>4, k-granule k8 = t&15.
// Image: chunk ch = c>>6, nl = c&63; granule slot = k8 ^ (nl&15).
__global__ void prep_coords(const float* __restrict__ coords,
                            unsigned short* __restrict__ Bh,
                            unsigned short* __restrict__ Bl,
                            float* __restrict__ c2, int* __restrict__ counter) {
    int t = blockIdx.x * blockDim.x + threadIdx.x;
    if (t == 0) *counter = 0;
    if (t >= C * 16) return;
    int c  = t >> 4;
    int k8 = t & 15;
    float v[8];
    *(float4*)(v)     = *(const float4*)(coords + (size_t)c * D + k8 * 8);
    *(float4*)(v + 4) = *(const float4*)(coords + (size_t)c * D + k8 * 8 + 4);
    short8 hi, lo;
    split8(v, &hi, &lo);
    int ch = c >> 6, nl = c & 63;
    size_t off = (size_t)ch * (NCH * 128) + ((size_t)nl * 16 + (k8 ^ (nl & 15))) * 8;
    *(short8*)(Bh + off) = hi;
    *(short8*)(Bl + off) = lo;
    float p = 0.f;
#pragma unroll
    for (int j = 0; j < 8; ++j) p = fmaf(v[j], v[j], p);
#pragma unroll
    for (int m = 1; m <= 8; m <<= 1) p += __shfl_xor(p, m, 64);
    if (k8 == 0) c2[c] = p + BIAS;
}

// ---------------- main kernel ----------------

__global__ __launch_bounds__(256, 3) void centroid_fast(
        const float* __restrict__ latent,
        const unsigned short* __restrict__ Bh_img,
        const unsigned short* __restrict__ Bl_img,
        const float* __restrict__ c2g,
        int* __restrict__ out,
        int* __restrict__ counter,
        int* __restrict__ worklist) {
    __shared__ __align__(16) unsigned short Bh[NCH * 128], Bl[NCH * 128]; // 32 KB
    __shared__ float sc2[NCH];

    const int tid  = threadIdx.x;
    const int wid  = tid >> 6;            // wave 0..3 -> rows wid*32..wid*32+31
    const int lane = tid & 63;
    const int q    = lane >> 4, lr = lane & 15;
    const int row_block = blockIdx.x * 128;

    // A fragments: lane holds A[m = lr][k = ks*32 + q*8 .. +8] for rows
    // wid*32 + mt*16 + lr -> 8 consecutive floats, loaded directly, split hi/lo.
    short8 Ah[2][4], Al[2][4];
#pragma unroll
    for (int mt = 0; mt < 2; ++mt) {
        const float* rp = latent + (size_t)(row_block + wid * 32 + mt * 16 + lr) * D;
#pragma unroll
        for (int ks = 0; ks < 4; ++ks) {
            float v[8];
            *(float4*)(v)     = *(const float4*)(rp + ks * 32 + q * 8);
            *(float4*)(v + 4) = *(const float4*)(rp + ks * 32 + q * 8 + 4);
            split8(v, &Ah[mt][ks], &Al[mt][ks]);
        }
    }

    // packed (score|idx) min-chains
    float b1[8], b2[8];
#pragma unroll
    for (int s = 0; s < 8; ++s) { b1[s] = 3.4e38f; b2[s] = 3.4e38f; }

    for (int ch = 0; ch < NCHUNKS; ++ch) {
        __syncthreads();   // prior chunk's ds_reads done
        {   // stage 16 KB hi + 16 KB lo via async DMA: wave wid copies its
            // quarter, 1 KB per instr, LDS dst = uniform base + lane*16
            const unsigned short* gh =
                Bh_img + (size_t)ch * (NCH * 128) + wid * 2048 + lane * 8;
            const unsigned short* gl =
                Bl_img + (size_t)ch * (NCH * 128) + wid * 2048 + lane * 8;
#pragma unroll
            for (int j = 0; j < 4; ++j) {
                async_copy16(gh + j * 512, Bh + wid * 2048 + j * 512);
                async_copy16(gl + j * 512, Bl + wid * 2048 + j * 512);
            }
            if (tid < NCH) sc2[tid] = c2g[ch * NCH + tid];
        }
        __syncthreads();   // drains DMA (vmcnt) + sc2

#pragma unroll
        for (int nt = 0; nt < 4; ++nt) {
            const int nl = nt * 16 + lr;
            f32x4 acc[2];
#pragma unroll
            for (int mt = 0; mt < 2; ++mt) acc[mt] = (f32x4){0.f, 0.f, 0.f, 0.f};
#pragma unroll
            for (int ks = 0; ks < 4; ++ks) {
                const int xv = ((ks * 4) | q) ^ lr;     // swizzle: conflict-free
                const int e  = nl * 128 + xv * 8;
                short8 bh = *(const short8*)(Bh + e);
                short8 bl = *(const short8*)(Bl + e);
#pragma unroll
                for (int mt = 0; mt < 2; ++mt) {
                    acc[mt] = __builtin_amdgcn_mfma_f32_16x16x32_bf16(Ah[mt][ks], bh, acc[mt], 0, 0, 0);
                    acc[mt] = __builtin_amdgcn_mfma_f32_16x16x32_bf16(Ah[mt][ks], bl, acc[mt], 0, 0, 0);
                    acc[mt] = __builtin_amdgcn_mfma_f32_16x16x32_bf16(Al[mt][ks], bh, acc[mt], 0, 0, 0);
                }
            }
            const float c2v = sc2[nl];                // biased: always > 0
            const unsigned idx = (unsigned)(ch * NCH + nl);   // 11 bits
#pragma unroll
            for (int mt = 0; mt < 2; ++mt)
#pragma unroll
                for (int r = 0; r < 4; ++r) {
                    int slot = mt * 4 + r;
                    float s = fmaf(-2.f, acc[mt][r], c2v);
                    float v = __uint_as_float(
                        (__float_as_uint(s) & 0xFFFFF800u) | idx);
                    b2[slot] = fminf(b2[slot], fmaxf(v, b1[slot]));
                    b1[slot] = fminf(b1[slot], v);
                }
        }
    }

    // butterfly over the 16 col-residue lanes (packed values: min == lex-min)
#pragma unroll
    for (int m = 1; m <= 8; m <<= 1) {
#pragma unroll
        for (int s = 0; s < 8; ++s) {
            float o1 = __shfl_xor(b1[s], m, 64);
            float o2 = __shfl_xor(b2[s], m, 64);
            b2[s] = fminf(fminf(b2[s], o2), fmaxf(b1[s], o1));
            b1[s] = fminf(b1[s], o1);
        }
    }
    // slot s canonical in lane lr==s; row = wid*32 + (s>>2)*16 + q*4 + (s&3)
#pragma unroll
    for (int s = 0; s < 8; ++s) {
        if (lr == s) {
            int row = row_block + wid * 32 + (s >> 2) * 16 + q * 4 + (s & 3);
            out[row] = (int)(__float_as_uint(b1[s]) & 0x7FFu);
            if (b2[s] - b1[s] < MARGIN) {
                int w = atomicAdd(counter, 1);
                if (w < WL_CAP) worklist[w] = row;
            }
        }
    }
}

// ---------------- fp64 refine (batched: 4 rows per block) ----------------

__global__ __launch_bounds__(256) void refine_fp64(
        const float* __restrict__ latent, const float* __restrict__ coords,
        const int* __restrict__ worklist, const int* __restrict__ counter,
        int wl_cap, int* __restrict__ out) {
    __shared__ float4 xs4[4][32];      // 4 latent rows
    __shared__ double rv[256];
    __shared__ int    ri[256];
    __shared__ int    rows_s[4];

    const int tid = threadIdx.x;
    int n = *counter;
    if (n > wl_cap) n = wl_cap;

    for (int g0 = blockIdx.x * 4; g0 < n; g0 += gridDim.x * 4) {
        int nr = n - g0; if (nr > 4) nr = 4;
        __syncthreads();                 // guard xs4/rows_s reuse
        if (tid < nr) rows_s[tid] = worklist[g0 + tid];
        __syncthreads();
        for (int i = tid; i < nr * 32; i += 256) {
            int j = i >> 5, k4 = i & 31;
            xs4[j][k4] = *(const float4*)(latent + (size_t)rows_s[j] * D + k4 * 4);
        }
        __syncthreads();

        double best[4];
        int    bix[4];
#pragma unroll
        for (int j = 0; j < 4; ++j) { best[j] = 1.0e300; bix[j] = 0; }

        for (int c = tid; c < C; c += 256) {
            const float4* cp = (const float4*)(coords + (size_t)c * D);
            double s[4] = {0.0, 0.0, 0.0, 0.0};
#pragma unroll 4
            for (int k4 = 0; k4 < 32; ++k4) {
                float4 v = cp[k4];
#pragma unroll
                for (int j = 0; j < 4; ++j) {
                    float4 x = xs4[j][k4];   // j >= nr reads garbage; discarded
                    double d0 = (double)x.x - (double)v.x;
                    double d1 = (double)x.y - (double)v.y;
                    double d2 = (double)x.z - (double)v.z;
                    double d3 = (double)x.w - (double)v.w;
                    s[j] = fma(d0, d0, s[j]); s[j] = fma(d1, d1, s[j]);
                    s[j] = fma(d2, d2, s[j]); s[j] = fma(d3, d3, s[j]);
                }
            }
#pragma unroll
            for (int j = 0; j < 4; ++j)
                if (s[j] < best[j]) { best[j] = s[j]; bix[j] = c; }
        }

        for (int j = 0; j < 4; ++j) {
            if (j >= nr) break;          // nr block-uniform
            rv[tid] = best[j];
            ri[tid] = bix[j];
            __syncthreads();
            for (int off = 128; off > 0; off >>= 1) {
                if (tid < off) {
                    double ov = rv[tid + off];
                    int    oi = ri[tid + off];
                    if (ov < rv[tid] || (ov == rv[tid] && oi < ri[tid])) {
                        rv[tid] = ov; ri[tid] = oi;
                    }
                }
                __syncthreads();
            }
            if (tid == 0) out[rows_s[j]] = ri[0];
            __syncthreads();
        }
    }
}

extern "C" void kernel_launch(void* const* d_in, const int* in_sizes, int n_in,
                              void* d_out, int out_size, void* d_ws, size_t ws_size,
                              hipStream_t stream) {
    const float* latent = (const float*)d_in[0];
    const float* coords = (const float*)d_in[1];
    int*         out    = (int*)d_out;

    char* ws = (char*)d_ws;
    float* c2      = (float*)ws;
    int*   counter = (int*)(ws + WS_CNT);
    int*   wl      = (int*)(ws + WS_WL);
    unsigned short* Bh = (unsigned short*)(ws + WS_BH);
    unsigned short* Bl = (unsigned short*)(ws + WS_BL);
    const int n_rows = in_sizes[0] / D;   // 131072

    prep_coords<<<(C * 16) / 256, 256, 0, stream>>>(coords, Bh, Bl, c2, counter);
    centroid_fast<<<n_rows / 128, 256, 0, stream>>>(latent, Bh, Bl, c2, out,
                                                    counter, wl);
    refine_fp64<<<512, 256, 0, stream>>>(latent, coords, wl, counter, WL_CAP, out);
}

// Round 10
// 331.217 us; speedup vs baseline: 1.5216x; 1.5216x over previous
//
#include <hip/hip_runtime.h>

// Centroids: argmin_c ||latent[r] - coords[c]||^2, 131072 rows x 2048 coords, D=128.
//
// prep_coords: coords -> bf16 hi/lo "B images" (XOR-swizzled granules: contiguous
//   staging AND conflict-free frag ds_read_b128), + c2, counter=0.
// centroid_fast: wave owns 32 rows x all 64 chunk-cols; A frags bf16x2 in VGPRs.
//   B staged via __builtin_amdgcn_global_load_lds width=16 (R9 win: staging VALU
//   ~0). bf16x2 3-pass MFMA (Ahh+Ahl+Alh). EXACT epilogue (R9 lesson: packing the
//   index into score mantissa forces margin >= pack bucket 0.125 -> 5% flag rate
//   -> 270 us refine; exact cmp/cndmask + MARGIN=0.02 flags ~0.4%).
// refine_fp64: batched 4 rows/block exact fp64 argmin for flagged rows.
//
// ws layout (bytes): 0 c2 | 8192 counter | 16384 worklist(128KB) |
//                    262144 Bh (512KB) | 786432 Bl (512KB) | end 1310720

constexpr int D = 128;
constexpr int C = 2048;
constexpr int NCH = 64;            // coords per chunk
constexpr int NCHUNKS = C / NCH;   // 32
constexpr float MARGIN = 0.02f;    // bf16x2 worst-case score err ~6e-3 -> 3x headroom
constexpr int WL_CAP = 32768;

constexpr size_t WS_CNT = 8192;
constexpr size_t WS_WL  = 16384;
constexpr size_t WS_BH  = 262144;
constexpr size_t WS_BL  = 786432;

typedef __attribute__((ext_vector_type(8))) short short8;
typedef __attribute__((ext_vector_type(4))) float f32x4;

__device__ inline unsigned short bf16_rne(float x) {
    unsigned u = __float_as_uint(x);
    u += 0x7FFFu + ((u >> 16) & 1u);
    return (unsigned short)(u >> 16);
}
__device__ inline float bf16_to_f(unsigned short h) {
    return __uint_as_float(((unsigned)h) << 16);
}
__device__ inline void split8(const float* v, short8* hi, short8* lo) {
#pragma unroll
    for (int j = 0; j < 8; ++j) {
        unsigned short h = bf16_rne(v[j]);
        (*hi)[j] = (short)h;
        (*lo)[j] = (short)bf16_rne(v[j] - bf16_to_f(h));
    }
}

// async 16B/lane global->LDS DMA; LDS dst = wave-uniform base + lane*16
__device__ inline void async_copy16(const void* g, void* l) {
    __builtin_amdgcn_global_load_lds(
        (const __attribute__((address_space(1))) void*)g,
        (__attribute__((address_space(3))) void*)l, 16, 0, 0);
}

// ---------------- prep: B images + c2 ----------------
// 32768 threads: thread t -> coord c = t>>4, k-granule k8 = t&15.
// Image: chunk ch = c>>6, nl = c&63; granule slot = k8 ^ (nl&15).
__global__ void prep_coords(const float* __restrict__ coords,
                            unsigned short* __restrict__ Bh,
                            unsigned short* __restrict__ Bl,
                            float* __restrict__ c2, int* __restrict__ counter) {
    int t = blockIdx.x * blockDim.x + threadIdx.x;
    if (t == 0) *counter = 0;
    if (t >= C * 16) return;
    int c  = t >> 4;
    int k8 = t & 15;
    float v[8];
    *(float4*)(v)     = *(const float4*)(coords + (size_t)c * D + k8 * 8);
    *(float4*)(v + 4) = *(const float4*)(coords + (size_t)c * D + k8 * 8 + 4);
    short8 hi, lo;
    split8(v, &hi, &lo);
    int ch = c >> 6, nl = c & 63;
    size_t off = (size_t)ch * (NCH * 128) + ((size_t)nl * 16 + (k8 ^ (nl & 15))) * 8;
    *(short8*)(Bh + off) = hi;
    *(short8*)(Bl + off) = lo;
    float p = 0.f;
#pragma unroll
    for (int j = 0; j < 8; ++j) p = fmaf(v[j], v[j], p);
#pragma unroll
    for (int m = 1; m <= 8; m <<= 1) p += __shfl_xor(p, m, 64);
    if (k8 == 0) c2[c] = p;
}

// ---------------- main kernel ----------------

__global__ __launch_bounds__(256, 3) void centroid_fast(
        const float* __restrict__ latent,
        const unsigned short* __restrict__ Bh_img,
        const unsigned short* __restrict__ Bl_img,
        const float* __restrict__ c2g,
        int* __restrict__ out,
        int* __restrict__ counter,
        int* __restrict__ worklist) {
    __shared__ __align__(16) unsigned short Bh[NCH * 128], Bl[NCH * 128]; // 32 KB
    __shared__ float sc2[NCH];

    const int tid  = threadIdx.x;
    const int wid  = tid >> 6;            // wave 0..3 -> rows wid*32..wid*32+31
    const int lane = tid & 63;
    const int q    = lane >> 4, lr = lane & 15;
    const int row_block = blockIdx.x * 128;

    // A fragments: lane holds A[m = lr][k = ks*32 + q*8 .. +8] for rows
    // wid*32 + mt*16 + lr -> 8 consecutive floats, loaded directly, split hi/lo.
    short8 Ah[2][4], Al[2][4];
#pragma unroll
    for (int mt = 0; mt < 2; ++mt) {
        const float* rp = latent + (size_t)(row_block + wid * 32 + mt * 16 + lr) * D;
#pragma unroll
        for (int ks = 0; ks < 4; ++ks) {
            float v[8];
            *(float4*)(v)     = *(const float4*)(rp + ks * 32 + q * 8);
            *(float4*)(v + 4) = *(const float4*)(rp + ks * 32 + q * 8 + 4);
            split8(v, &Ah[mt][ks], &Al[mt][ks]);
        }
    }

    float b1[8], b2[8];
    int   bidx[8];
#pragma unroll
    for (int s = 0; s < 8; ++s) { b1[s] = 3.4e38f; b2[s] = 3.4e38f; bidx[s] = 0; }

    for (int ch = 0; ch < NCHUNKS; ++ch) {
        __syncthreads();   // prior chunk's ds_reads done
        {   // stage 16 KB hi + 16 KB lo via async DMA: wave wid copies its
            // quarter, 1 KB per instr, LDS dst = uniform base + lane*16
            const unsigned short* gh =
                Bh_img + (size_t)ch * (NCH * 128) + wid * 2048 + lane * 8;
            const unsigned short* gl =
                Bl_img + (size_t)ch * (NCH * 128) + wid * 2048 + lane * 8;
#pragma unroll
            for (int j = 0; j < 4; ++j) {
                async_copy16(gh + j * 512, Bh + wid * 2048 + j * 512);
                async_copy16(gl + j * 512, Bl + wid * 2048 + j * 512);
            }
            if (tid < NCH) sc2[tid] = c2g[ch * NCH + tid];
        }
        __syncthreads();   // drains DMA (vmcnt) + sc2

#pragma unroll
        for (int nt = 0; nt < 4; ++nt) {
            const int nl = nt * 16 + lr;
            f32x4 acc[2];
#pragma unroll
            for (int mt = 0; mt < 2; ++mt) acc[mt] = (f32x4){0.f, 0.f, 0.f, 0.f};
#pragma unroll
            for (int ks = 0; ks < 4; ++ks) {
                const int xv = ((ks * 4) | q) ^ lr;     // swizzle: conflict-free
                const int e  = nl * 128 + xv * 8;
                short8 bh = *(const short8*)(Bh + e);
                short8 bl = *(const short8*)(Bl + e);
#pragma unroll
                for (int mt = 0; mt < 2; ++mt) {
                    acc[mt] = __builtin_amdgcn_mfma_f32_16x16x32_bf16(Ah[mt][ks], bh, acc[mt], 0, 0, 0);
                    acc[mt] = __builtin_amdgcn_mfma_f32_16x16x32_bf16(Ah[mt][ks], bl, acc[mt], 0, 0, 0);
                    acc[mt] = __builtin_amdgcn_mfma_f32_16x16x32_bf16(Al[mt][ks], bh, acc[mt], 0, 0, 0);
                }
            }
            const float c2v = sc2[nl];
            const int n_global = ch * NCH + nl;
#pragma unroll
            for (int mt = 0; mt < 2; ++mt)
#pragma unroll
                for (int r = 0; r < 4; ++r) {
                    int slot = mt * 4 + r;
                    float s = fmaf(-2.f, acc[mt][r], c2v);
                    bool lt = s < b1[slot];
                    float t = fmaxf(s, b1[slot]);
                    b2[slot]   = fminf(b2[slot], t);
                    b1[slot]   = fminf(s, b1[slot]);
                    bidx[slot] = lt ? n_global : bidx[slot];
                }
        }
    }

    // butterfly over the 16 col-residue lanes
#pragma unroll
    for (int m = 1; m <= 8; m <<= 1) {
#pragma unroll
        for (int s = 0; s < 8; ++s) {
            float ob1 = __shfl_xor(b1[s], m, 64);
            float ob2 = __shfl_xor(b2[s], m, 64);
            int   oix = __shfl_xor(bidx[s], m, 64);
            float mx  = fmaxf(b1[s], ob1);
            b2[s] = fminf(fminf(b2[s], ob2), mx);
            bool take = (ob1 < b1[s]) || (ob1 == b1[s] && oix < bidx[s]);
            b1[s]   = take ? ob1 : b1[s];
            bidx[s] = take ? oix : bidx[s];
        }
    }
    // slot s canonical in lane lr==s; row = wid*32 + (s>>2)*16 + q*4 + (s&3)
#pragma unroll
    for (int s = 0; s < 8; ++s) {
        if (lr == s) {
            int row = row_block + wid * 32 + (s >> 2) * 16 + q * 4 + (s & 3);
            out[row] = bidx[s];
            if (b2[s] - b1[s] < MARGIN) {
                int w = atomicAdd(counter, 1);
                if (w < WL_CAP) worklist[w] = row;
            }
        }
    }
}

// ---------------- fp64 refine (batched: 4 rows per block) ----------------

__global__ __launch_bounds__(256) void refine_fp64(
        const float* __restrict__ latent, const float* __restrict__ coords,
        const int* __restrict__ worklist, const int* __restrict__ counter,
        int wl_cap, int* __restrict__ out) {
    __shared__ float4 xs4[4][32];      // 4 latent rows
    __shared__ double rv[256];
    __shared__ int    ri[256];
    __shared__ int    rows_s[4];

    const int tid = threadIdx.x;
    int n = *counter;
    if (n > wl_cap) n = wl_cap;

    for (int g0 = blockIdx.x * 4; g0 < n; g0 += gridDim.x * 4) {
        int nr = n - g0; if (nr > 4) nr = 4;
        __syncthreads();                 // guard xs4/rows_s reuse
        if (tid < nr) rows_s[tid] = worklist[g0 + tid];
        __syncthreads();
        for (int i = tid; i < nr * 32; i += 256) {
            int j = i >> 5, k4 = i & 31;
            xs4[j][k4] = *(const float4*)(latent + (size_t)rows_s[j] * D + k4 * 4);
        }
        __syncthreads();

        double best[4];
        int    bix[4];
#pragma unroll
        for (int j = 0; j < 4; ++j) { best[j] = 1.0e300; bix[j] = 0; }

        for (int c = tid; c < C; c += 256) {
            const float4* cp = (const float4*)(coords + (size_t)c * D);
            double s[4] = {0.0, 0.0, 0.0, 0.0};
#pragma unroll 4
            for (int k4 = 0; k4 < 32; ++k4) {
                float4 v = cp[k4];
#pragma unroll
                for (int j = 0; j < 4; ++j) {
                    float4 x = xs4[j][k4];   // j >= nr reads garbage; discarded
                    double d0 = (double)x.x - (double)v.x;
                    double d1 = (double)x.y - (double)v.y;
                    double d2 = (double)x.z - (double)v.z;
                    double d3 = (double)x.w - (double)v.w;
                    s[j] = fma(d0, d0, s[j]); s[j] = fma(d1, d1, s[j]);
                    s[j] = fma(d2, d2, s[j]); s[j] = fma(d3, d3, s[j]);
                }
            }
#pragma unroll
            for (int j = 0; j < 4; ++j)
                if (s[j] < best[j]) { best[j] = s[j]; bix[j] = c; }
        }

        for (int j = 0; j < 4; ++j) {
            if (j >= nr) break;          // nr block-uniform
            rv[tid] = best[j];
            ri[tid] = bix[j];
            __syncthreads();
            for (int off = 128; off > 0; off >>= 1) {
                if (tid < off) {
                    double ov = rv[tid + off];
                    int    oi = ri[tid + off];
                    if (ov < rv[tid] || (ov == rv[tid] && oi < ri[tid])) {
                        rv[tid] = ov; ri[tid] = oi;
                    }
                }
                __syncthreads();
            }
            if (tid == 0) out[rows_s[j]] = ri[0];
            __syncthreads();
        }
    }
}

extern "C" void kernel_launch(void* const* d_in, const int* in_sizes, int n_in,
                              void* d_out, int out_size, void* d_ws, size_t ws_size,
                              hipStream_t stream) {
    const float* latent = (const float*)d_in[0];
    const float* coords = (const float*)d_in[1];
    int*         out    = (int*)d_out;

    char* ws = (char*)d_ws;
    float* c2      = (float*)ws;
    int*   counter = (int*)(ws + WS_CNT);
    int*   wl      = (int*)(ws + WS_WL);
    unsigned short* Bh = (unsigned short*)(ws + WS_BH);
    unsigned short* Bl = (unsigned short*)(ws + WS_BL);
    const int n_rows = in_sizes[0] / D;   // 131072

    prep_coords<<<(C * 16) / 256, 256, 0, stream>>>(coords, Bh, Bl, c2, counter);
    centroid_fast<<<n_rows / 128, 256, 0, stream>>>(latent, Bh, Bl, c2, out,
                                                    counter, wl);
    refine_fp64<<<512, 256, 0, stream>>>(latent, coords, wl, counter, WL_CAP, out);
}